// Round 12
// baseline (120.541 us; speedup 1.0000x reference)
//
#include <hip/hip_runtime.h>
#include <stdint.h>
#include <stddef.h>

#define SS 1024
#define BB 16
#define DD 512
#define HH 8
#define DHH 64

typedef __attribute__((ext_vector_type(8))) short bf16x8;
typedef __attribute__((ext_vector_type(4))) float f32x4;
typedef __attribute__((ext_vector_type(16))) float f32x16;
typedef __attribute__((ext_vector_type(4))) float float4v;
typedef __attribute__((ext_vector_type(4))) unsigned short us4;

__device__ __forceinline__ unsigned short f2bf(float f) {
  union { float f; unsigned int u; } v; v.f = f;
  unsigned int x = v.u;
  return (unsigned short)((x + 0x7FFFu + ((x >> 16) & 1u)) >> 16);
}

// async global->LDS, 16B per lane; LDS dest is wave-uniform base (+lane*16 implicit)
#define GLDS16(dst, src)                                                                  \
  __builtin_amdgcn_global_load_lds(                                                      \
      (const __attribute__((address_space(1))) unsigned int*)(const void*)(src),         \
      (__attribute__((address_space(3))) unsigned int*)(void*)(dst), 16, 0, 0)

// ---------------- Kernel A: f32 -> bf16 conversion + mask-to-logadd -------------------
// wq pre-scaled by 2/(8*ln2) so attn gets u = e^{2x} = exp2(sc) directly (x = s/8).
// maskq[b][s] = mask ? 0 : -16384  (folded into the final exp2 argument by one FMA).
__global__ void cvt_kernel(const float* __restrict__ x,
                           const float* __restrict__ wq,
                           const float* __restrict__ wk,
                           const float* __restrict__ wv,
                           const float* __restrict__ mask,
                           unsigned short* __restrict__ xb,
                           unsigned short* __restrict__ wb,
                           float* __restrict__ maskq) {
  const int i = blockIdx.x * 256 + threadIdx.x;   // one float4 per thread
  const int n_x4 = (SS * BB * DD) / 4;            // 2,097,152
  const int n_w4 = 3 * 65536;                     // 196,608
  if (i < n_x4) {
    float4v v = ((const float4v*)x)[i];
    us4 o;
    o[0] = f2bf(v[0]); o[1] = f2bf(v[1]); o[2] = f2bf(v[2]); o[3] = f2bf(v[3]);
    ((us4*)xb)[i] = o;
  } else if (i < n_x4 + n_w4) {
    const int j = i - n_x4;            // 0..196607
    const int sel = j >> 16;           // which weight (65536 float4 each)
    const int off4 = j & 65535;
    const float* wsrc = (sel == 0) ? wq : ((sel == 1) ? wk : wv);
    const float scale = (sel == 0) ? 0.36067376022224085f : 1.0f;
    float4v v = ((const float4v*)wsrc)[off4];
    us4 o;
    o[0] = f2bf(v[0] * scale); o[1] = f2bf(v[1] * scale);
    o[2] = f2bf(v[2] * scale); o[3] = f2bf(v[3] * scale);
    ((us4*)wb)[(sel << 16) + off4] = o;
  } else {
    const int j = i - n_x4 - n_w4;     // 0..4095
    float4v mv = ((const float4v*)mask)[j];
    float4v o;
#pragma unroll
    for (int c = 0; c < 4; ++c) o[c] = (mv[c] > 0.5f) ? 0.f : -16384.f;
    ((float4v*)maskq)[j] = o;
  }
}

// ---------------- Kernel B: projection GEMM  Y[s,f] = sum_d x[s,b,d] * w[f,d] ---------
// 1D grid 1536, z->XCD swizzle: all 32 (bm,bn) blocks of one z = (b,wsel) land on ONE
// XCD so its L2 serves the 8MB/z of tile re-reads (was: round-robin -> every XCD
// re-fetched every z's panels from L3; proj was L3-BW-bound).
// 128x128 tile, BK=64, XOR-swizzled At/Bt; At/Bt UNION OT epilogue pool (36.9KB).
// Outputs: wsel 0/1 -> q/k as [bh][s][e] bf16 ; wsel 2 -> vT as [bh][e][s] bf16.
__global__ __launch_bounds__(256) void proj_kernel(
    const unsigned short* __restrict__ xb,
    const unsigned short* __restrict__ wb,
    unsigned short* __restrict__ qb,
    unsigned short* __restrict__ kb,
    unsigned short* __restrict__ vt) {
  const int id = blockIdx.x;
  const int xcd = id & 7;
  const int j = id >> 3;               // 0..191
  const int z = (j >> 5) * 8 + xcd;    // 6 z-groups per XCD, bijective over 0..47
  const int xy = j & 31;
  const int bm = (xy & 7) * 128;
  const int bn = (xy >> 3) * 128;
  const int b = z / 3;
  const int wsel = z % 3;

  __shared__ unsigned short pool[4 * 64 * 72];   // 36864B; At/Bt alias OT (disjoint in time)
  unsigned short* At = pool;                      // 128 rows x 64 cols (swizzled chunks)
  unsigned short* Bt = pool + 8192;               // 128 rows x 64 cols

  const int tid = threadIdx.x;
  const int w = tid >> 6;
  const int lane = tid & 63;

  const unsigned short* wptr = wb + wsel * (512 * DD);

  f32x4 acc[4][4];
#pragma unroll
  for (int mi = 0; mi < 4; ++mi)
#pragma unroll
    for (int ni = 0; ni < 4; ++ni) acc[mi][ni] = (f32x4){0.f, 0.f, 0.f, 0.f};

  const int m0 = (w & 1) * 64;
  const int n0 = (w >> 1) * 64;

  for (int kt = 0; kt < 8; ++kt) {
    // stage 128x64 A and B tiles; physical chunk (r, c&7) holds logical (r, (c&7)^(r&7))
#pragma unroll
    for (int i = 0; i < 4; ++i) {
      const int c = i * 256 + tid;           // 16B-chunk index 0..1023
      const int r = c >> 3;                  // row 0..127
      const int c8 = (c & 7) ^ (r & 7);      // inverse-swizzled source chunk
      GLDS16(&At[(i * 256 + w * 64) * 8],
             xb + (size_t)(bm + r) * (BB * DD) + b * DD + kt * 64 + c8 * 8);
      GLDS16(&Bt[(i * 256 + w * 64) * 8],
             wptr + (size_t)(bn + r) * DD + kt * 64 + c8 * 8);
    }
    __syncthreads();
#pragma unroll
    for (int ks = 0; ks < 2; ++ks) {
      // logical 16B chunk j2 = ks*4 + (lane>>4), physical j2 ^ (row&7); row&7 == lane&7
      const int sw = ((ks * 4 + (lane >> 4)) ^ (lane & 7)) << 4;
      bf16x8 af[4], bfr[4];
#pragma unroll
      for (int mi = 0; mi < 4; ++mi)
        af[mi] = *(const bf16x8*)((const char*)At + (m0 + mi * 16 + (lane & 15)) * 128 + sw);
#pragma unroll
      for (int ni = 0; ni < 4; ++ni)
        bfr[ni] = *(const bf16x8*)((const char*)Bt + (n0 + ni * 16 + (lane & 15)) * 128 + sw);
#pragma unroll
      for (int mi = 0; mi < 4; ++mi)
#pragma unroll
        for (int ni = 0; ni < 4; ++ni)
          acc[mi][ni] =
              __builtin_amdgcn_mfma_f32_16x16x32_bf16(af[mi], bfr[ni], acc[mi][ni], 0, 0, 0);
    }
    __syncthreads();   // last iter: also orders final At/Bt reads before OT overwrite
  }

  // epilogue: per-wave LDS transpose (OT aliases At/Bt; per-wave region, same-wave RAW)
  const int h = (bn + n0) >> 6;                 // wave's 64 features = exactly one head
  unsigned short* OTw = pool + w * 4608;        // 64*72 elems per wave
  if (wsel != 2) {
    // OT[row=s_local][col=e]
#pragma unroll
    for (int mi = 0; mi < 4; ++mi)
#pragma unroll
      for (int ni = 0; ni < 4; ++ni)
#pragma unroll
        for (int jj = 0; jj < 4; ++jj)
          OTw[(mi * 16 + (lane >> 4) * 4 + jj) * 72 + ni * 16 + (lane & 15)] =
              f2bf(acc[mi][ni][jj]);
  } else {
    // OT[row=e][col=s_local]  (transposed store, 4 consecutive s pack to 8B)
#pragma unroll
    for (int mi = 0; mi < 4; ++mi)
#pragma unroll
      for (int ni = 0; ni < 4; ++ni) {
        us4 pk;
#pragma unroll
        for (int jj = 0; jj < 4; ++jj) pk[jj] = f2bf(acc[mi][ni][jj]);
        *(us4*)&OTw[(ni * 16 + (lane & 15)) * 72 + mi * 16 + (lane >> 4) * 4] = pk;
      }
  }
  unsigned short* gout = (wsel == 0) ? qb : ((wsel == 1) ? kb : vt);
#pragma unroll
  for (int pass = 0; pass < 8; ++pass) {
    const int row = pass * 8 + (lane >> 3);
    bf16x8 vrow = *(const bf16x8*)&OTw[row * 72 + (lane & 7) * 8];
    size_t dst;
    if (wsel != 2)
      dst = ((size_t)(b * HH + h) * SS + (size_t)(bm + m0 + row)) * DHH + (lane & 7) * 8;
    else
      dst = ((size_t)(b * HH + h) * DHH + (size_t)row) * SS + (bm + m0) + (lane & 7) * 8;
    *(bf16x8*)&gout[dst] = vrow;
  }
}

// ---------------- Kernel C: fused attention, v12 --------------------------------------
// R10/R11 structure + rowsum-via-MFMA: the 32 serial `rs += p` adds per kt (dependent
// v_add chain on the binding VALU pipe) become 4 MFMA/kt against a ones-B-frag,
// accumulating into rsacc whose reg->q mapping matches accO exactly. End shuffles and
// rs_s LDS removed; denominator now quantization-consistent with the bf16 numerator.
__global__ __launch_bounds__(256, 4) void attn_kernel(
    const unsigned short* __restrict__ qb,
    const unsigned short* __restrict__ kb,
    const unsigned short* __restrict__ vt,
    const float* __restrict__ maskq,
    float* __restrict__ out) {
  // bijective XCD decode: 1024 blocks = 8 XCDs x (16 bh x 8 qt)
  const int id = blockIdx.x;
  const int xcd = id & 7;
  const int slot = id >> 3;
  const int bh = xcd * 16 + (slot >> 3);
  const int qt = slot & 7;
  const int b = bh >> 3;
  const int h = bh & 7;
  const int tid = threadIdx.x;
  const int w = tid >> 6;
  const int lane = tid & 63;
  const int l31 = lane & 31;
  const int hi32 = lane >> 5;
  // sigma: swap bits 2/3 of l31 -> C-tile regs r=0..7 hold keys 8*hi+0..7 (A-frag layout)
  const int sl = (l31 & 0x13) | ((l31 & 4) << 1) | ((l31 & 8) >> 1);

  __shared__ unsigned short Ks[2][64 * 64];  // [key][dh], 128B rows, XOR-swizzled
  __shared__ unsigned short Vs[2][64 * 64];  // [e][key],  128B rows, XOR-swizzled

  const size_t base_qk = (size_t)bh * SS * DHH;
  const int q0 = qt * 128 + w * 32;

  // Q B-frags: aq[ks]: q-row = q0+l31, dh = ks*16 + hi32*8 .. +8
  bf16x8 aq[4];
  {
    const unsigned short* qp = qb + base_qk + (size_t)(q0 + l31) * DHH + hi32 * 8;
    aq[0] = *(const bf16x8*)(qp);
    aq[1] = *(const bf16x8*)(qp + 16);
    aq[2] = *(const bf16x8*)(qp + 32);
    aq[3] = *(const bf16x8*)(qp + 48);
  }

  // ones B-fragment for rowsum MFMA (bf16 1.0 = 0x3F80)
  union { unsigned short u[8]; bf16x8 v; } ones_;
#pragma unroll
  for (int i = 0; i < 8; ++i) ones_.u[i] = 0x3F80;
  const bf16x8 ones = ones_.v;

  // staging: wave w fills rows [16w, 16w+16) via 2 GLDS16 each for K and V.
  // Source col inverse-swizzled so swizzled reads see linear data (rule 21).
  const int sr0 = w * 16 + (lane >> 3);               // rows sr0 and sr0+8
  const int sxb = (((lane & 7) ^ (lane >> 3)) << 4);  // swizzle class same for both rows
  const unsigned short* ksrc0 = kb + base_qk + (size_t)sr0 * DHH + (sxb >> 1);
  const unsigned short* ksrc1 = ksrc0 + 8 * DHH;
  const unsigned short* vsrc0 =
      vt + (size_t)bh * DHH * SS + (size_t)sr0 * SS + (sxb >> 1);
  const unsigned short* vsrc1 = vsrc0 + 8 * SS;

#define STAGE(bb, kt2)                                                       \
  do {                                                                       \
    GLDS16(&Ks[bb][(w * 16) * 64], ksrc0 + (size_t)(kt2) * (64 * DHH));      \
    GLDS16(&Ks[bb][(w * 16 + 8) * 64], ksrc1 + (size_t)(kt2) * (64 * DHH));  \
    GLDS16(&Vs[bb][(w * 16) * 64], vsrc0 + (size_t)(kt2) * 64);              \
    GLDS16(&Vs[bb][(w * 16 + 8) * 64], vsrc1 + (size_t)(kt2) * 64);          \
  } while (0)

  STAGE(0, 0);

  f32x16 accO[2];
#pragma unroll
  for (int n = 0; n < 2; ++n)
#pragma unroll
    for (int i = 0; i < 16; ++i) accO[n][i] = 0.f;
  f32x16 rsacc = {};
  const float* mrow = maskq + b * SS;

  __syncthreads();   // drains vmcnt: tile 0 resident

  int buf = 0;
  for (int kt = 0; kt < 16; ++kt) {
    if (kt < 15) STAGE(buf ^ 1, kt + 1);   // prefetch next tile (in flight all phase)
    const char* Kb = (const char*)&Ks[buf][0];
    const char* Vb = (const char*)&Vs[buf][0];

    // ---- QK for BOTH 32-key tiles up front (independent MFMA chains) ----
    const int ksw = (sl & 7) << 4;         // (T*32+sl)&7 == sl&7
    f32x16 scT[2];
    scT[0] = (f32x16){};
    scT[1] = (f32x16){};
    __builtin_amdgcn_s_setprio(1);
#pragma unroll
    for (int ks = 0; ks < 4; ++ks) {
      bf16x8 kfA = *(const bf16x8*)(Kb + (0 + sl) * 128 + ((ks * 32 + hi32 * 16) ^ ksw));
      scT[0] = __builtin_amdgcn_mfma_f32_32x32x16_bf16(kfA, aq[ks], scT[0], 0, 0, 0);
    }
#pragma unroll
    for (int ks = 0; ks < 4; ++ks) {
      bf16x8 kfB = *(const bf16x8*)(Kb + (32 + sl) * 128 + ((ks * 32 + hi32 * 16) ^ ksw));
      scT[1] = __builtin_amdgcn_mfma_f32_32x32x16_bf16(kfB, aq[ks], scT[1], 0, 0, 0);
    }
    __builtin_amdgcn_s_setprio(0);

#pragma unroll
    for (int T = 0; T < 2; ++T) {
      const f32x16 sc = scT[T];
      // softmax: u = exp2(sc) (= e^{2x}); r = quad-rcp(1+u);
      // p = exp2(fma(r, -2*log2e, maskq))  (== mask ? e^{tanh(x)-1} : ~0)
      unsigned int pu[16];
#pragma unroll
      for (int g = 0; g < 4; ++g) {
        // keys for regs r=g*4+i: kt*64 + T*32 + (g>>1)*16 + hi32*8 + (g&1)*4 + i
        float4v mv = *(const float4v*)&mrow[kt * 64 + T * 32 + (g >> 1) * 16 +
                                            hi32 * 8 + (g & 1) * 4];
        float a0 = 1.f + __builtin_amdgcn_exp2f(sc[g * 4 + 0]);
        float a1 = 1.f + __builtin_amdgcn_exp2f(sc[g * 4 + 1]);
        float a2 = 1.f + __builtin_amdgcn_exp2f(sc[g * 4 + 2]);
        float a3 = 1.f + __builtin_amdgcn_exp2f(sc[g * 4 + 3]);
        float p01 = a0 * a1, p23 = a2 * a3;
        float rq = __builtin_amdgcn_rcpf(p01 * p23);
        float r01 = p23 * rq, r23 = p01 * rq;
        float r[4];
        r[0] = a1 * r01; r[1] = a0 * r01; r[2] = a3 * r23; r[3] = a2 * r23;
#pragma unroll
        for (int i = 0; i < 4; ++i) {
          float p = __builtin_amdgcn_exp2f(__builtin_fmaf(r[i], -2.88539008178f, mv[i]));
          union { float f; unsigned int u; } cv;
          cv.f = p;
          pu[g * 4 + i] = cv.u;
        }
      }
      // pack to bf16 pairs (truncate; bias cancels in p*v / sum(p)) — A-frag laid already
      union { unsigned int u[4]; bf16x8 v; } f0, f1;
#pragma unroll
      for (int m = 0; m < 4; ++m) {
        f0.u[m] = __builtin_amdgcn_perm(pu[2 * m + 1], pu[2 * m], 0x07060302u);
        f1.u[m] = __builtin_amdgcn_perm(pu[8 + 2 * m + 1], pu[8 + 2 * m], 0x07060302u);
      }
      // rowsum via MFMA (B=ones) + PV: A = P frags, B = V from swizzled LDS
      __builtin_amdgcn_s_setprio(1);
      rsacc = __builtin_amdgcn_mfma_f32_32x32x16_bf16(f0.v, ones, rsacc, 0, 0, 0);
      rsacc = __builtin_amdgcn_mfma_f32_32x32x16_bf16(f1.v, ones, rsacc, 0, 0, 0);
#pragma unroll
      for (int n = 0; n < 2; ++n) {
        const int vrow = n * 32 + l31;
        const int vsw = (vrow & 7) << 4;
        bf16x8 bv0 = *(const bf16x8*)(Vb + vrow * 128 + (((T * 2 + 0) * 32 + hi32 * 16) ^ vsw));
        bf16x8 bv1 = *(const bf16x8*)(Vb + vrow * 128 + (((T * 2 + 1) * 32 + hi32 * 16) ^ vsw));
        accO[n] = __builtin_amdgcn_mfma_f32_32x32x16_bf16(f0.v, bv0, accO[n], 0, 0, 0);
        accO[n] = __builtin_amdgcn_mfma_f32_32x32x16_bf16(f1.v, bv1, accO[n], 0, 0, 0);
      }
      __builtin_amdgcn_s_setprio(0);
    }
    __syncthreads();   // drains vmcnt (next tile landed) + protects buffer flip
    buf ^= 1;
  }
#undef STAGE

  // epilogue: rsacc reg r holds rowsum for q = g*8 + hi32*4 + i (same mapping as accO)
#pragma unroll
  for (int g = 0; g < 4; ++g)
#pragma unroll
    for (int i = 0; i < 4; ++i) {
      const int r = g * 4 + i;
      const float rinv = __builtin_amdgcn_rcpf(rsacc[r]);
      const int qrow = q0 + g * 8 + hi32 * 4 + i;
#pragma unroll
      for (int n = 0; n < 2; ++n)
        out[((size_t)qrow * BB + b) * DD + h * DHH + n * 32 + l31] = accO[n][r] * rinv;
    }
}

extern "C" void kernel_launch(void* const* d_in, const int* in_sizes, int n_in,
                              void* d_out, int out_size, void* d_ws, size_t ws_size,
                              hipStream_t stream) {
  const float* x = (const float*)d_in[0];
  const float* mask = (const float*)d_in[1];
  const float* wq = (const float*)d_in[2];
  const float* wk = (const float*)d_in[3];
  const float* wv = (const float*)d_in[4];
  float* out = (float*)d_out;

  char* ws = (char*)d_ws;
  unsigned short* xb = (unsigned short*)(ws);                         // 16 MB
  unsigned short* wb = (unsigned short*)(ws + (16ull << 20));         // 1.5 MB
  float* maskq = (float*)(ws + (17ull << 20) + (512ull << 10));       // 64 KB @17.5MB
  unsigned short* qb = (unsigned short*)(ws + (18ull << 20));         // 16 MB
  unsigned short* kb = (unsigned short*)(ws + (34ull << 20));         // 16 MB
  unsigned short* vt = (unsigned short*)(ws + (50ull << 20));         // 16 MB -> 66 MB

  cvt_kernel<<<dim3(8976), 256, 0, stream>>>(x, wq, wk, wv, mask, xb, wb, maskq);
  proj_kernel<<<dim3(1536), 256, 0, stream>>>(xb, wb, qb, kb, vt);
  attn_kernel<<<dim3(1024), 256, 0, stream>>>(qb, kb, vt, maskq, out);
}

// Round 13
// 114.737 us; speedup vs baseline: 1.0506x; 1.0506x over previous
//
#include <hip/hip_runtime.h>
#include <stdint.h>
#include <stddef.h>

#define SS 1024
#define BB 16
#define DD 512
#define HH 8
#define DHH 64

typedef __attribute__((ext_vector_type(8))) short bf16x8;
typedef __attribute__((ext_vector_type(4))) float f32x4;
typedef __attribute__((ext_vector_type(16))) float f32x16;
typedef __attribute__((ext_vector_type(4))) float float4v;
typedef __attribute__((ext_vector_type(4))) unsigned short us4;

__device__ __forceinline__ unsigned short f2bf(float f) {
  union { float f; unsigned int u; } v; v.f = f;
  unsigned int x = v.u;
  return (unsigned short)((x + 0x7FFFu + ((x >> 16) & 1u)) >> 16);
}

// async global->LDS, 16B per lane; LDS dest is wave-uniform base (+lane*16 implicit)
#define GLDS16(dst, src)                                                                  \
  __builtin_amdgcn_global_load_lds(                                                      \
      (const __attribute__((address_space(1))) unsigned int*)(const void*)(src),         \
      (__attribute__((address_space(3))) unsigned int*)(void*)(dst), 16, 0, 0)

// ---------------- Kernel A: f32 -> bf16 conversion + mask-to-logadd -------------------
// wq pre-scaled by 2/(8*ln2) so attn gets u = e^{2x} = exp2(sc) directly (x = s/8).
// maskq[b][s] = mask ? 0 : -16384  (folded into the final exp2 argument by one FMA).
__global__ void cvt_kernel(const float* __restrict__ x,
                           const float* __restrict__ wq,
                           const float* __restrict__ wk,
                           const float* __restrict__ wv,
                           const float* __restrict__ mask,
                           unsigned short* __restrict__ xb,
                           unsigned short* __restrict__ wb,
                           float* __restrict__ maskq) {
  const int i = blockIdx.x * 256 + threadIdx.x;   // one float4 per thread
  const int n_x4 = (SS * BB * DD) / 4;            // 2,097,152
  const int n_w4 = 3 * 65536;                     // 196,608
  if (i < n_x4) {
    float4v v = ((const float4v*)x)[i];
    us4 o;
    o[0] = f2bf(v[0]); o[1] = f2bf(v[1]); o[2] = f2bf(v[2]); o[3] = f2bf(v[3]);
    ((us4*)xb)[i] = o;
  } else if (i < n_x4 + n_w4) {
    const int j = i - n_x4;            // 0..196607
    const int sel = j >> 16;           // which weight (65536 float4 each)
    const int off4 = j & 65535;
    const float* wsrc = (sel == 0) ? wq : ((sel == 1) ? wk : wv);
    const float scale = (sel == 0) ? 0.36067376022224085f : 1.0f;
    float4v v = ((const float4v*)wsrc)[off4];
    us4 o;
    o[0] = f2bf(v[0] * scale); o[1] = f2bf(v[1] * scale);
    o[2] = f2bf(v[2] * scale); o[3] = f2bf(v[3] * scale);
    ((us4*)wb)[(sel << 16) + off4] = o;
  } else {
    const int j = i - n_x4 - n_w4;     // 0..4095
    float4v mv = ((const float4v*)mask)[j];
    float4v o;
#pragma unroll
    for (int c = 0; c < 4; ++c) o[c] = (mv[c] > 0.5f) ? 0.f : -16384.f;
    ((float4v*)maskq)[j] = o;
  }
}

// ---------------- Kernel B: projection GEMM  Y[s,f] = sum_d x[s,b,d] * w[f,d] ---------
// 1D grid 1536, z->XCD swizzle: all 32 (bm,bn) blocks of one z = (b,wsel) land on ONE
// XCD so its L2 serves the 8MB/z of tile re-reads.
// 128x128 tile, BK=64, XOR-swizzled At/Bt; At/Bt UNION OT epilogue pool (36.9KB).
// Outputs: wsel 0/1 -> q/k as [bh][s][e] bf16 ; wsel 2 -> vT as [bh][e][s] bf16.
__global__ __launch_bounds__(256) void proj_kernel(
    const unsigned short* __restrict__ xb,
    const unsigned short* __restrict__ wb,
    unsigned short* __restrict__ qb,
    unsigned short* __restrict__ kb,
    unsigned short* __restrict__ vt) {
  const int id = blockIdx.x;
  const int xcd = id & 7;
  const int j = id >> 3;               // 0..191
  const int z = (j >> 5) * 8 + xcd;    // 6 z-groups per XCD, bijective over 0..47
  const int xy = j & 31;
  const int bm = (xy & 7) * 128;
  const int bn = (xy >> 3) * 128;
  const int b = z / 3;
  const int wsel = z % 3;

  __shared__ unsigned short pool[4 * 64 * 72];   // 36864B; At/Bt alias OT (disjoint in time)
  unsigned short* At = pool;                      // 128 rows x 64 cols (swizzled chunks)
  unsigned short* Bt = pool + 8192;               // 128 rows x 64 cols

  const int tid = threadIdx.x;
  const int w = tid >> 6;
  const int lane = tid & 63;

  const unsigned short* wptr = wb + wsel * (512 * DD);

  f32x4 acc[4][4];
#pragma unroll
  for (int mi = 0; mi < 4; ++mi)
#pragma unroll
    for (int ni = 0; ni < 4; ++ni) acc[mi][ni] = (f32x4){0.f, 0.f, 0.f, 0.f};

  const int m0 = (w & 1) * 64;
  const int n0 = (w >> 1) * 64;

  for (int kt = 0; kt < 8; ++kt) {
    // stage 128x64 A and B tiles; physical chunk (r, c&7) holds logical (r, (c&7)^(r&7))
#pragma unroll
    for (int i = 0; i < 4; ++i) {
      const int c = i * 256 + tid;           // 16B-chunk index 0..1023
      const int r = c >> 3;                  // row 0..127
      const int c8 = (c & 7) ^ (r & 7);      // inverse-swizzled source chunk
      GLDS16(&At[(i * 256 + w * 64) * 8],
             xb + (size_t)(bm + r) * (BB * DD) + b * DD + kt * 64 + c8 * 8);
      GLDS16(&Bt[(i * 256 + w * 64) * 8],
             wptr + (size_t)(bn + r) * DD + kt * 64 + c8 * 8);
    }
    __syncthreads();
#pragma unroll
    for (int ks = 0; ks < 2; ++ks) {
      // logical 16B chunk j2 = ks*4 + (lane>>4), physical j2 ^ (row&7); row&7 == lane&7
      const int sw = ((ks * 4 + (lane >> 4)) ^ (lane & 7)) << 4;
      bf16x8 af[4], bfr[4];
#pragma unroll
      for (int mi = 0; mi < 4; ++mi)
        af[mi] = *(const bf16x8*)((const char*)At + (m0 + mi * 16 + (lane & 15)) * 128 + sw);
#pragma unroll
      for (int ni = 0; ni < 4; ++ni)
        bfr[ni] = *(const bf16x8*)((const char*)Bt + (n0 + ni * 16 + (lane & 15)) * 128 + sw);
#pragma unroll
      for (int mi = 0; mi < 4; ++mi)
#pragma unroll
        for (int ni = 0; ni < 4; ++ni)
          acc[mi][ni] =
              __builtin_amdgcn_mfma_f32_16x16x32_bf16(af[mi], bfr[ni], acc[mi][ni], 0, 0, 0);
    }
    __syncthreads();   // last iter: also orders final At/Bt reads before OT overwrite
  }

  // epilogue: per-wave LDS transpose (OT aliases At/Bt; per-wave region, same-wave RAW)
  const int h = (bn + n0) >> 6;                 // wave's 64 features = exactly one head
  unsigned short* OTw = pool + w * 4608;        // 64*72 elems per wave
  if (wsel != 2) {
    // OT[row=s_local][col=e]
#pragma unroll
    for (int mi = 0; mi < 4; ++mi)
#pragma unroll
      for (int ni = 0; ni < 4; ++ni)
#pragma unroll
        for (int jj = 0; jj < 4; ++jj)
          OTw[(mi * 16 + (lane >> 4) * 4 + jj) * 72 + ni * 16 + (lane & 15)] =
              f2bf(acc[mi][ni][jj]);
  } else {
    // OT[row=e][col=s_local]  (transposed store, 4 consecutive s pack to 8B)
#pragma unroll
    for (int mi = 0; mi < 4; ++mi)
#pragma unroll
      for (int ni = 0; ni < 4; ++ni) {
        us4 pk;
#pragma unroll
        for (int jj = 0; jj < 4; ++jj) pk[jj] = f2bf(acc[mi][ni][jj]);
        *(us4*)&OTw[(ni * 16 + (lane & 15)) * 72 + mi * 16 + (lane >> 4) * 4] = pk;
      }
  }
  unsigned short* gout = (wsel == 0) ? qb : ((wsel == 1) ? kb : vt);
#pragma unroll
  for (int pass = 0; pass < 8; ++pass) {
    const int row = pass * 8 + (lane >> 3);
    bf16x8 vrow = *(const bf16x8*)&OTw[row * 72 + (lane & 7) * 8];
    size_t dst;
    if (wsel != 2)
      dst = ((size_t)(b * HH + h) * SS + (size_t)(bm + m0 + row)) * DHH + (lane & 7) * 8;
    else
      dst = ((size_t)(b * HH + h) * DHH + (size_t)row) * SS + (bm + m0) + (lane & 7) * 8;
    *(bf16x8*)&gout[dst] = vrow;
  }
}

// ---------------- Kernel C: fused attention (R10/R11 measured optimum) ----------------
__global__ __launch_bounds__(256, 4) void attn_kernel(
    const unsigned short* __restrict__ qb,
    const unsigned short* __restrict__ kb,
    const unsigned short* __restrict__ vt,
    const float* __restrict__ maskq,
    float* __restrict__ out) {
  // bijective XCD decode: 1024 blocks = 8 XCDs x (16 bh x 8 qt)
  const int id = blockIdx.x;
  const int xcd = id & 7;
  const int slot = id >> 3;
  const int bh = xcd * 16 + (slot >> 3);
  const int qt = slot & 7;
  const int b = bh >> 3;
  const int h = bh & 7;
  const int tid = threadIdx.x;
  const int w = tid >> 6;
  const int lane = tid & 63;
  const int l31 = lane & 31;
  const int hi32 = lane >> 5;
  // sigma: swap bits 2/3 of l31 -> C-tile regs r=0..7 hold keys 8*hi+0..7 (A-frag layout)
  const int sl = (l31 & 0x13) | ((l31 & 4) << 1) | ((l31 & 8) >> 1);

  __shared__ unsigned short Ks[2][64 * 64];  // [key][dh], 128B rows, XOR-swizzled
  __shared__ unsigned short Vs[2][64 * 64];  // [e][key],  128B rows, XOR-swizzled
  __shared__ float rs_s[4][32];              // per-wave rowsum reciprocals

  const size_t base_qk = (size_t)bh * SS * DHH;
  const int q0 = qt * 128 + w * 32;

  // Q B-frags: aq[ks]: q-row = q0+l31, dh = ks*16 + hi32*8 .. +8
  bf16x8 aq[4];
  {
    const unsigned short* qp = qb + base_qk + (size_t)(q0 + l31) * DHH + hi32 * 8;
    aq[0] = *(const bf16x8*)(qp);
    aq[1] = *(const bf16x8*)(qp + 16);
    aq[2] = *(const bf16x8*)(qp + 32);
    aq[3] = *(const bf16x8*)(qp + 48);
  }

  // staging: wave w fills rows [16w, 16w+16) via 2 GLDS16 each for K and V.
  // Source col inverse-swizzled so swizzled reads see linear data (rule 21).
  const int sr0 = w * 16 + (lane >> 3);               // rows sr0 and sr0+8
  const int sxb = (((lane & 7) ^ (lane >> 3)) << 4);  // swizzle class same for both rows
  const unsigned short* ksrc0 = kb + base_qk + (size_t)sr0 * DHH + (sxb >> 1);
  const unsigned short* ksrc1 = ksrc0 + 8 * DHH;
  const unsigned short* vsrc0 =
      vt + (size_t)bh * DHH * SS + (size_t)sr0 * SS + (sxb >> 1);
  const unsigned short* vsrc1 = vsrc0 + 8 * SS;

#define STAGE(bb, kt2)                                                       \
  do {                                                                       \
    GLDS16(&Ks[bb][(w * 16) * 64], ksrc0 + (size_t)(kt2) * (64 * DHH));      \
    GLDS16(&Ks[bb][(w * 16 + 8) * 64], ksrc1 + (size_t)(kt2) * (64 * DHH));  \
    GLDS16(&Vs[bb][(w * 16) * 64], vsrc0 + (size_t)(kt2) * 64);              \
    GLDS16(&Vs[bb][(w * 16 + 8) * 64], vsrc1 + (size_t)(kt2) * 64);          \
  } while (0)

  STAGE(0, 0);

  f32x16 accO[2];
#pragma unroll
  for (int n = 0; n < 2; ++n)
#pragma unroll
    for (int i = 0; i < 16; ++i) accO[n][i] = 0.f;
  float rs = 0.f;
  const float* mrow = maskq + b * SS;

  __syncthreads();   // drains vmcnt: tile 0 resident

  int buf = 0;
  for (int kt = 0; kt < 16; ++kt) {
    if (kt < 15) STAGE(buf ^ 1, kt + 1);   // prefetch next tile (in flight all phase)
    const char* Kb = (const char*)&Ks[buf][0];
    const char* Vb = (const char*)&Vs[buf][0];

    // ---- QK for BOTH 32-key tiles up front (independent MFMA chains) ----
    const int ksw = (sl & 7) << 4;         // (T*32+sl)&7 == sl&7
    f32x16 scT[2];
    scT[0] = (f32x16){};
    scT[1] = (f32x16){};
    __builtin_amdgcn_s_setprio(1);
#pragma unroll
    for (int ks = 0; ks < 4; ++ks) {
      bf16x8 kfA = *(const bf16x8*)(Kb + (0 + sl) * 128 + ((ks * 32 + hi32 * 16) ^ ksw));
      scT[0] = __builtin_amdgcn_mfma_f32_32x32x16_bf16(kfA, aq[ks], scT[0], 0, 0, 0);
    }
#pragma unroll
    for (int ks = 0; ks < 4; ++ks) {
      bf16x8 kfB = *(const bf16x8*)(Kb + (32 + sl) * 128 + ((ks * 32 + hi32 * 16) ^ ksw));
      scT[1] = __builtin_amdgcn_mfma_f32_32x32x16_bf16(kfB, aq[ks], scT[1], 0, 0, 0);
    }
    __builtin_amdgcn_s_setprio(0);

#pragma unroll
    for (int T = 0; T < 2; ++T) {
      const f32x16 sc = scT[T];
      // softmax: u = exp2(sc) (= e^{2x}); r = quad-rcp(1+u);
      // p = exp2(fma(r, -2*log2e, maskq))  (== mask ? e^{tanh(x)-1} : ~0)
      unsigned int pu[16];
#pragma unroll
      for (int g = 0; g < 4; ++g) {
        // keys for regs r=g*4+i: kt*64 + T*32 + (g>>1)*16 + hi32*8 + (g&1)*4 + i
        float4v mv = *(const float4v*)&mrow[kt * 64 + T * 32 + (g >> 1) * 16 +
                                            hi32 * 8 + (g & 1) * 4];
        float a0 = 1.f + __builtin_amdgcn_exp2f(sc[g * 4 + 0]);
        float a1 = 1.f + __builtin_amdgcn_exp2f(sc[g * 4 + 1]);
        float a2 = 1.f + __builtin_amdgcn_exp2f(sc[g * 4 + 2]);
        float a3 = 1.f + __builtin_amdgcn_exp2f(sc[g * 4 + 3]);
        float p01 = a0 * a1, p23 = a2 * a3;
        float rq = __builtin_amdgcn_rcpf(p01 * p23);
        float r01 = p23 * rq, r23 = p01 * rq;
        float r[4];
        r[0] = a1 * r01; r[1] = a0 * r01; r[2] = a3 * r23; r[3] = a2 * r23;
#pragma unroll
        for (int i = 0; i < 4; ++i) {
          float p = __builtin_amdgcn_exp2f(__builtin_fmaf(r[i], -2.88539008178f, mv[i]));
          rs += p;
          union { float f; unsigned int u; } cv;
          cv.f = p;
          pu[g * 4 + i] = cv.u;
        }
      }
      // pack to bf16 pairs (truncate; bias cancels in p*v / sum(p)) — A-frag laid already
      union { unsigned int u[4]; bf16x8 v; } f0, f1;
#pragma unroll
      for (int m = 0; m < 4; ++m) {
        f0.u[m] = __builtin_amdgcn_perm(pu[2 * m + 1], pu[2 * m], 0x07060302u);
        f1.u[m] = __builtin_amdgcn_perm(pu[8 + 2 * m + 1], pu[8 + 2 * m], 0x07060302u);
      }
      // PV: A = P frags (keys T*32+0..15 / +16..31), B = V from swizzled LDS
      __builtin_amdgcn_s_setprio(1);
#pragma unroll
      for (int n = 0; n < 2; ++n) {
        const int vrow = n * 32 + l31;
        const int vsw = (vrow & 7) << 4;
        bf16x8 bv0 = *(const bf16x8*)(Vb + vrow * 128 + (((T * 2 + 0) * 32 + hi32 * 16) ^ vsw));
        bf16x8 bv1 = *(const bf16x8*)(Vb + vrow * 128 + (((T * 2 + 1) * 32 + hi32 * 16) ^ vsw));
        accO[n] = __builtin_amdgcn_mfma_f32_32x32x16_bf16(f0.v, bv0, accO[n], 0, 0, 0);
        accO[n] = __builtin_amdgcn_mfma_f32_32x32x16_bf16(f1.v, bv1, accO[n], 0, 0, 0);
      }
      __builtin_amdgcn_s_setprio(0);
    }
    __syncthreads();   // drains vmcnt (next tile landed) + protects buffer flip
    buf ^= 1;
  }
#undef STAGE

  // rowsum: lane's rs covers its hi32-half of keys for q=l31; combine + invert
  rs += __shfl_xor(rs, 32, 64);
  if (hi32 == 0) rs_s[w][l31] = __builtin_amdgcn_rcpf(rs);
  float4v ri[4];
#pragma unroll
  for (int g = 0; g < 4; ++g) ri[g] = *(const float4v*)&rs_s[w][g * 8 + hi32 * 4];

#pragma unroll
  for (int n = 0; n < 2; ++n)
#pragma unroll
    for (int g = 0; g < 4; ++g)
#pragma unroll
      for (int i = 0; i < 4; ++i) {
        const int qrow = q0 + g * 8 + hi32 * 4 + i;
        out[((size_t)qrow * BB + b) * DD + h * DHH + n * 32 + l31] =
            accO[n][g * 4 + i] * ri[g][i];
      }
}

extern "C" void kernel_launch(void* const* d_in, const int* in_sizes, int n_in,
                              void* d_out, int out_size, void* d_ws, size_t ws_size,
                              hipStream_t stream) {
  const float* x = (const float*)d_in[0];
  const float* mask = (const float*)d_in[1];
  const float* wq = (const float*)d_in[2];
  const float* wk = (const float*)d_in[3];
  const float* wv = (const float*)d_in[4];
  float* out = (float*)d_out;

  char* ws = (char*)d_ws;
  unsigned short* xb = (unsigned short*)(ws);                         // 16 MB
  unsigned short* wb = (unsigned short*)(ws + (16ull << 20));         // 1.5 MB
  float* maskq = (float*)(ws + (17ull << 20) + (512ull << 10));       // 64 KB @17.5MB
  unsigned short* qb = (unsigned short*)(ws + (18ull << 20));         // 16 MB
  unsigned short* kb = (unsigned short*)(ws + (34ull << 20));         // 16 MB
  unsigned short* vt = (unsigned short*)(ws + (50ull << 20));         // 16 MB -> 66 MB

  cvt_kernel<<<dim3(8976), 256, 0, stream>>>(x, wq, wk, wv, mask, xb, wb, maskq);
  proj_kernel<<<dim3(1536), 256, 0, stream>>>(xb, wb, qb, kb, vt);
  attn_kernel<<<dim3(1024), 256, 0, stream>>>(qb, kb, vt, maskq, out);
}